// Round 8
// baseline (122.208 us; speedup 1.0000x reference)
//
#include <hip/hip_runtime.h>

#define B 256
#define EPSV 1e-5f

// ---------- output offsets (f32 elements) ----------
#define OFF_ASSIGN 0
#define OFF_LOSS   256
#define OFF_ACT4   257
#define OFF_L1     2817
#define OFF_L2     12847873
#define OFF_L3     14486273

__device__ inline void wave_reduce2(float& s, float& q) {
#pragma unroll
    for (int o = 32; o > 0; o >>= 1) {
        s += __shfl_down(s, o, 64);
        q += __shfl_down(q, o, 64);
    }
}

// one-shot: w1 [120][400] -> w1T [400][120]; k3s [512][120] -> k3sT [120][512]
__global__ __launch_bounds__(256) void transpose_kernel(
        const float* __restrict__ w1, const float* __restrict__ k3,
        float* __restrict__ w1t, float* __restrict__ k3st) {
    int idx = blockIdx.x * 256 + threadIdx.x;
    if (idx < 48000) {
        int c = idx / 120, o = idx % 120;
        w1t[idx] = w1[o * 400 + c];
    } else if (idx < 48000 + 61440) {
        int j = idx - 48000;
        int c = j >> 9, k = j & 511;
        k3st[j] = k3[k * 120 + c];
    }
}

// conv1: [B,3,32,32] -> raw c1 [B,6,28,28] + per-(b,c) sum/sumsq partials
__global__ __launch_bounds__(256) void conv1_kernel(
        const float* __restrict__ inp, const float* __restrict__ w,
        const float* __restrict__ bias, float* __restrict__ c1,
        float* __restrict__ part) {
    int bc = blockIdx.x; int b = bc / 6, c = bc % 6;
    int tid = threadIdx.x;
    __shared__ float ws[75];
    __shared__ float rs[4], rq[4];
    if (tid < 75) ws[tid] = w[c * 75 + tid];
    __syncthreads();
    const float* ip = inp + b * 3072;
    float bs = bias[c];
    float s = 0.f, sq = 0.f;
    for (int hw = tid; hw < 784; hw += 256) {
        int oh = hw / 28, ow = hw % 28;
        float acc = bs;
#pragma unroll
        for (int ic = 0; ic < 3; ++ic) {
            const float* ipc = ip + ic * 1024 + oh * 32 + ow;
            const float* wc = ws + ic * 25;
#pragma unroll
            for (int kh = 0; kh < 5; ++kh)
#pragma unroll
                for (int kw = 0; kw < 5; ++kw)
                    acc += ipc[kh * 32 + kw] * wc[kh * 5 + kw];
        }
        c1[bc * 784 + hw] = acc;
        s += acc; sq += acc * acc;
    }
    wave_reduce2(s, sq);
    if ((tid & 63) == 0) { rs[tid >> 6] = s; rq[tid >> 6] = sq; }
    __syncthreads();
    if (tid == 0) {
        part[bc * 2]     = rs[0] + rs[1] + rs[2] + rs[3];
        part[bc * 2 + 1] = rq[0] + rq[1] + rq[2] + rq[3];
    }
}

// per-channel stats from B partials; grid = C blocks, 256 thr (one per b)
__global__ void stats_kernel(const float* __restrict__ part, float* __restrict__ stats,
                             int C, float invN) {
    int c = blockIdx.x, tid = threadIdx.x;
    float s = part[(tid * C + c) * 2];
    float q = part[(tid * C + c) * 2 + 1];
    wave_reduce2(s, q);
    __shared__ float rs[4], rq[4];
    if ((tid & 63) == 0) { rs[tid >> 6] = s; rq[tid >> 6] = q; }
    __syncthreads();
    if (tid == 0) {
        float S = rs[0] + rs[1] + rs[2] + rs[3];
        float Q = rq[0] + rq[1] + rq[2] + rq[3];
        float m = S * invN;
        float v = Q * invN - m * m;
        stats[c] = m; stats[C + c] = v;
    }
}

// logits1 (+fused BN-relu-pool -> x1 in 1-of-49 blocks)
__global__ __launch_bounds__(256) void logits1_kernel(
        const float* __restrict__ c1, const float* __restrict__ st,
        const float* __restrict__ g, const float* __restrict__ bb,
        const float* __restrict__ k1s, float* __restrict__ outL1,
        float* __restrict__ x1) {
    __shared__ float sk[384];
    __shared__ float ssc[6], ssh[6];
    int tid = threadIdx.x;
    if (tid < 6) {
        float m = st[tid], v = st[6 + tid];
        float sc = g[tid] * rsqrtf(v + EPSV);
        ssc[tid] = sc; ssh[tid] = bb[tid] - m * sc;
    }
    for (int i = tid; i < 384; i += 256) sk[i] = k1s[i];
    __syncthreads();
    int t = blockIdx.x * 256 + tid;          // B*16*784 = 3211264
    int hw = t % 784; int u = t / 784; int kq = u & 15; int b = u >> 4;
    float a[6];
#pragma unroll
    for (int c = 0; c < 6; ++c)
        a[c] = c1[(b * 6 + c) * 784 + hw] * ssc[c] + ssh[c];
    float* op = outL1 + (long)b * 50176 + kq * 3136 + hw;
#pragma unroll
    for (int j = 0; j < 4; ++j) {
        int k = kq * 4 + j;
        float s = 0.f;
#pragma unroll
        for (int c = 0; c < 6; ++c) { float d = a[c] - sk[k * 6 + c]; s += d * d; }
        op[j * 784] = -sqrtf(s);
    }
    // fused BN+relu+pool: first block of each batch writes x1[b]
    if ((blockIdx.x % 49) == 0) {
        int bb2 = blockIdx.x / 49;
        const float* cp = c1 + bb2 * 4704;
        for (int i = tid; i < 1176; i += 256) {
            int c = i / 196, p = i % 196, ph = p / 14, pw = p % 14;
            const float* ap = cp + c * 784 + ph * 56 + pw * 2;
            float sc = ssc[c], sh = ssh[c];
            float v0 = ap[0] * sc + sh, v1 = ap[1] * sc + sh;
            float v2 = ap[28] * sc + sh, v3 = ap[29] * sc + sh;
            x1[bb2 * 1176 + i] = fmaxf(fmaxf(fmaxf(v0, v1), fmaxf(v2, v3)), 0.f);
        }
    }
}

// conv2: x1 [B,6,14,14] -> raw c2 [B,16,10,10] + partials; block=(b,c), 128 thr
__global__ __launch_bounds__(128) void conv2_kernel(
        const float* __restrict__ x1, const float* __restrict__ w,
        const float* __restrict__ bias, float* __restrict__ c2,
        float* __restrict__ part) {
    int bc = blockIdx.x; int b = bc >> 4, c = bc & 15;
    int tid = threadIdx.x;  // 128
    __shared__ float xs[1176];
    __shared__ float ws[150];
    __shared__ float rs[2], rq[2];
    for (int i = tid; i < 1176; i += 128) xs[i] = x1[b * 1176 + i];
    for (int i = tid; i < 150; i += 128) ws[i] = w[c * 150 + i];
    __syncthreads();
    float val = 0.f;
    if (tid < 100) {
        int oh = tid / 10, ow = tid % 10;
        float acc = bias[c];
#pragma unroll
        for (int ic = 0; ic < 6; ++ic) {
            const float* xp = xs + ic * 196 + oh * 14 + ow;
            const float* wp = ws + ic * 25;
#pragma unroll
            for (int kh = 0; kh < 5; ++kh)
#pragma unroll
                for (int kw = 0; kw < 5; ++kw)
                    acc += xp[kh * 14 + kw] * wp[kh * 5 + kw];
        }
        c2[bc * 100 + tid] = acc;
        val = acc;
    }
    float s = val, sq = val * val;
    wave_reduce2(s, sq);
    if ((tid & 63) == 0) { rs[tid >> 6] = s; rq[tid >> 6] = sq; }
    __syncthreads();
    if (tid == 0) {
        part[bc * 2]     = rs[0] + rs[1];
        part[bc * 2 + 1] = rq[0] + rq[1];
    }
}

// logits2 (+fused pool -> x2 in 1-of-25 blocks); act2 staged BN'd in LDS
__global__ __launch_bounds__(256) void logits2_kernel(
        const float* __restrict__ c2, const float* __restrict__ st,
        const float* __restrict__ g, const float* __restrict__ bb,
        const float* __restrict__ k2s, float* __restrict__ outL2,
        float* __restrict__ x2) {
    __shared__ float sk[1024];
    __shared__ float sa[1600];
    __shared__ float ssc[16], ssh[16];
    int tid = threadIdx.x;
    int t0 = blockIdx.x * 256;
    int b = t0 / 6400;                       // constant per block (6400 % 256 == 0)
    if (tid < 16) {
        float m = st[tid], v = st[16 + tid];
        float sc = g[tid] * rsqrtf(v + EPSV);
        ssc[tid] = sc; ssh[tid] = bb[tid] - m * sc;
    }
    for (int i = tid; i < 1024; i += 256) sk[i] = k2s[i];
    __syncthreads();
    for (int i = tid; i < 1600; i += 256) {
        int c = i / 100;
        sa[i] = c2[b * 1600 + i] * ssc[c] + ssh[c];
    }
    __syncthreads();
    int t = t0 + tid;
    int hw = t % 100; int k = (t / 100) & 63;
    float s = 0.f;
#pragma unroll
    for (int c = 0; c < 16; ++c) { float d = sa[c * 100 + hw] - sk[k * 16 + c]; s += d * d; }
    outL2[t] = -sqrtf(s);
    if ((blockIdx.x % 25) == 0) {            // fused relu+pool from BN'd LDS tile
        for (int i = tid; i < 400; i += 256) {
            int c = i / 25, p = i % 25, ph = p / 5, pw = p % 5;
            const float* ap = sa + c * 100 + ph * 20 + pw * 2;
            float m = fmaxf(fmaxf(ap[0], ap[1]), fmaxf(ap[10], ap[11]));
            x2[b * 400 + i] = fmaxf(m, 0.f);
        }
    }
}

// head: fc1 + act4 + logits3 + argmax + rank-based NG loss; block per b, 512 thr.
// ALL global reads coalesced via pre-transposed w1T [400][120] / k3sT [120][512]:
// lane index == output/key index, activations broadcast from LDS.
__global__ __launch_bounds__(512) void head_kernel(
        const float* __restrict__ x2, const float* __restrict__ w1t,
        const float* __restrict__ b1, const float* __restrict__ w2,
        const float* __restrict__ b2, const float* __restrict__ k3st,
        float* __restrict__ outAct4, float* __restrict__ outL3,
        float* __restrict__ outAssign, float* __restrict__ lossb) {
    int b = blockIdx.x, tid = threadIdx.x;
    int lane = tid & 63, wid = tid >> 6;
    __shared__ float xs[400];
    __shared__ float partq[4][128];
    __shared__ float a3r[120], a3p[120];
    __shared__ float sv[512];
    __shared__ float wsum[8], wmv[8];
    __shared__ int wmi[8];
    for (int i = tid; i < 400; i += 512) xs[i] = x2[b * 400 + i];
    __syncthreads();
    // fc1: 4-way K-split; thread (q = tid>>7, o = tid&127) does dims [q*100, q*100+100)
    // w1t reads: lanes have consecutive o -> coalesced; xs broadcast.
    {
        int o = tid & 127, q = tid >> 7;
        float s = 0.f;
        if (o < 120) {
            const float* wp = w1t + q * 100 * 120 + o;
            const float* xp = xs + q * 100;
#pragma unroll 10
            for (int c = 0; c < 100; ++c) s += xp[c] * wp[c * 120];
        }
        partq[q][o] = s;
    }
    __syncthreads();
    if (tid < 120) {
        float acc = partq[0][tid] + partq[1][tid] + partq[2][tid] + partq[3][tid] + b1[tid];
        a3r[tid] = acc;
        a3p[tid] = fmaxf(acc, 0.f);
    }
    __syncthreads();
    // logits3: thread = key; k3sT reads lane-consecutive (coalesced), a3r broadcast
    float v;
    {
        const float* kp = k3st + tid;
        float s = 0.f;
#pragma unroll 8
        for (int c = 0; c < 120; ++c) { float d = a3r[c] - kp[c * 512]; s += d * d; }
        v = -sqrtf(s);
        sv[tid] = v;
        outL3[b * 512 + tid] = v;
    }
    if (tid < 10) {                           // fc2 from relu(act3) — tiny, leave as-is
        float acc = b2[tid];
        const float* wp = w2 + tid * 120;
#pragma unroll 8
        for (int c = 0; c < 120; ++c) acc += a3p[c] * wp[c];
        outAct4[b * 10 + tid] = acc;
    }
    __syncthreads();
    // rank of this thread's value (ties by index) == its sorted position,
    // so sum v^2*exp(-rank) over threads == sum over sorted order.
    const float4* sv4 = reinterpret_cast<const float4*>(sv);
    int cnt = 0;
#pragma unroll 8
    for (int j4 = 0; j4 < 128; ++j4) {
        float4 o4 = sv4[j4];
        int jb = j4 * 4;
        cnt += (o4.x < v || (o4.x == v && jb < tid)) ? 1 : 0;
        cnt += (o4.y < v || (o4.y == v && jb + 1 < tid)) ? 1 : 0;
        cnt += (o4.z < v || (o4.z == v && jb + 2 < tid)) ? 1 : 0;
        cnt += (o4.w < v || (o4.w == v && jb + 3 < tid)) ? 1 : 0;
    }
    float contrib = v * v * expf(-(float)cnt);
    // per-wave sum + argmax (once), then cross-wave on thread 0
    float ssum = contrib;
#pragma unroll
    for (int o = 32; o > 0; o >>= 1) ssum += __shfl_down(ssum, o, 64);
    float mv = v; int mi = tid;
#pragma unroll
    for (int o = 32; o > 0; o >>= 1) {
        float ov = __shfl_down(mv, o, 64);
        int oi = __shfl_down(mi, o, 64);
        if (ov > mv || (ov == mv && oi < mi)) { mv = ov; mi = oi; }
    }
    if (lane == 0) { wsum[wid] = ssum; wmv[wid] = mv; wmi[wid] = mi; }
    __syncthreads();
    if (tid == 0) {
        float tot = 0.f;
        float bmv = wmv[0]; int bmi = wmi[0];
#pragma unroll
        for (int w = 0; w < 8; ++w) {
            tot += wsum[w];
            if (wmv[w] > bmv || (wmv[w] == bmv && wmi[w] < bmi)) { bmv = wmv[w]; bmi = wmi[w]; }
        }
        lossb[b] = tot;
        outAssign[b] = (float)bmi;
    }
}

__global__ void final_kernel(const float* __restrict__ loss_b, float* __restrict__ out_loss) {
    __shared__ float r[256];
    int tid = threadIdx.x;
    r[tid] = loss_b[tid];
    __syncthreads();
    for (int s = 128; s > 0; s >>= 1) {
        if (tid < s) r[tid] += r[tid + s];
        __syncthreads();
    }
    if (tid == 0) out_loss[0] = r[0] / 256.f;
}

extern "C" void kernel_launch(void* const* d_in, const int* in_sizes, int n_in,
                              void* d_out, int out_size, void* d_ws, size_t ws_size,
                              hipStream_t stream) {
    const float* inp = (const float*)d_in[0];
    const float* c1w = (const float*)d_in[1];
    const float* c1b = (const float*)d_in[2];
    const float* g1  = (const float*)d_in[3];
    const float* bb1 = (const float*)d_in[4];
    const float* c2w = (const float*)d_in[5];
    const float* c2b = (const float*)d_in[6];
    const float* g2  = (const float*)d_in[7];
    const float* bb2 = (const float*)d_in[8];
    const float* f1w = (const float*)d_in[9];
    const float* f1b = (const float*)d_in[10];
    const float* f2w = (const float*)d_in[11];
    const float* f2b = (const float*)d_in[12];
    const float* k1  = (const float*)d_in[13];
    const float* k2  = (const float*)d_in[14];
    const float* k3  = (const float*)d_in[15];
    float* out = (float*)d_out;

    // Stash raw c1 (1204224 f) and x1 (301056 f) in the logits2 output region
    // (1638400 f) — written only later in stream order, fully overwritten by logits2.
    float* c1raw = out + OFF_L2;               // 1204224
    float* x1    = c1raw + 1204224;            // 301056 (ends at 1505280 < 1638400)

    // workspace layout (floats) — ~633k floats = 2.53 MB
    float* W = (float*)d_ws;
    float* c2raw = W;                  // 409600
    float* x2    = c2raw + 409600;     // 102400
    float* part1 = x2 + 102400;        // 3072
    float* part2 = part1 + 3072;       // 8192
    float* st1   = part2 + 8192;       // 12
    float* st2   = st1 + 12;           // 32
    float* lossb = st2 + 32;           // 256
    float* w1t   = lossb + 256;        // 48000  (w1T [400][120])
    float* k3st  = w1t + 48000;        // 61440  (k3sT [120][512])

    transpose_kernel<<<428, 256, 0, stream>>>(f1w, k3, w1t, k3st);
    conv1_kernel<<<B * 6, 256, 0, stream>>>(inp, c1w, c1b, c1raw, part1);
    stats_kernel<<<6, 256, 0, stream>>>(part1, st1, 6, 1.f / 200704.f);
    logits1_kernel<<<12544, 256, 0, stream>>>(c1raw, st1, g1, bb1, k1, out + OFF_L1, x1);
    conv2_kernel<<<B * 16, 128, 0, stream>>>(x1, c2w, c2b, c2raw, part2);
    stats_kernel<<<16, 256, 0, stream>>>(part2, st2, 16, 1.f / 25600.f);
    logits2_kernel<<<6400, 256, 0, stream>>>(c2raw, st2, g2, bb2, k2, out + OFF_L2, x2);
    head_kernel<<<B, 512, 0, stream>>>(x2, w1t, f1b, f2w, f2b, k3st,
                                       out + OFF_ACT4, out + OFF_L3, out + OFF_ASSIGN, lossb);
    final_kernel<<<1, 256, 0, stream>>>(lossb, out + OFF_LOSS);
}

// Round 9
// 119.924 us; speedup vs baseline: 1.0190x; 1.0190x over previous
//
#include <hip/hip_runtime.h>

#define B 256
#define EPSV 1e-5f

// ---------- output offsets (f32 elements) ----------
#define OFF_ASSIGN 0
#define OFF_LOSS   256
#define OFF_ACT4   257
#define OFF_L1     2817
#define OFF_L2     12847873
#define OFF_L3     14486273

__device__ inline void wave_reduce2(float& s, float& q) {
#pragma unroll
    for (int o = 32; o > 0; o >>= 1) {
        s += __shfl_down(s, o, 64);
        q += __shfl_down(q, o, 64);
    }
}

// conv1 (blocks 0..1535) + one-shot w1/k3s transpose (blocks 1536..1963)
__global__ __launch_bounds__(256) void conv1_kernel(
        const float* __restrict__ inp, const float* __restrict__ w,
        const float* __restrict__ bias, float* __restrict__ c1,
        float* __restrict__ part,
        const float* __restrict__ w1, const float* __restrict__ k3,
        float* __restrict__ w1t, float* __restrict__ k3st) {
    int bc = blockIdx.x;
    int tid = threadIdx.x;
    if (bc >= 1536) {                        // transpose tail blocks
        int idx = (bc - 1536) * 256 + tid;
        if (idx < 48000) {
            int c = idx / 120, o = idx % 120;
            w1t[idx] = w1[o * 400 + c];
        } else if (idx < 48000 + 61440) {
            int j = idx - 48000;
            int c = j >> 9, k = j & 511;
            k3st[j] = k3[k * 120 + c];
        }
        return;
    }
    int b = bc / 6, c = bc % 6;
    __shared__ float ws[75];
    __shared__ float rs[4], rq[4];
    if (tid < 75) ws[tid] = w[c * 75 + tid];
    __syncthreads();
    const float* ip = inp + b * 3072;
    float bs = bias[c];
    float s = 0.f, sq = 0.f;
    for (int hw = tid; hw < 784; hw += 256) {
        int oh = hw / 28, ow = hw % 28;
        float acc = bs;
#pragma unroll
        for (int ic = 0; ic < 3; ++ic) {
            const float* ipc = ip + ic * 1024 + oh * 32 + ow;
            const float* wc = ws + ic * 25;
#pragma unroll
            for (int kh = 0; kh < 5; ++kh)
#pragma unroll
                for (int kw = 0; kw < 5; ++kw)
                    acc += ipc[kh * 32 + kw] * wc[kh * 5 + kw];
        }
        c1[bc * 784 + hw] = acc;
        s += acc; sq += acc * acc;
    }
    wave_reduce2(s, sq);
    if ((tid & 63) == 0) { rs[tid >> 6] = s; rq[tid >> 6] = sq; }
    __syncthreads();
    if (tid == 0) {
        part[bc * 2]     = rs[0] + rs[1] + rs[2] + rs[3];
        part[bc * 2 + 1] = rq[0] + rq[1] + rq[2] + rq[3];
    }
}

// per-channel stats from B partials; grid = C blocks, 256 thr (one per b)
__global__ void stats_kernel(const float* __restrict__ part, float* __restrict__ stats,
                             int C, float invN) {
    int c = blockIdx.x, tid = threadIdx.x;
    float s = part[(tid * C + c) * 2];
    float q = part[(tid * C + c) * 2 + 1];
    wave_reduce2(s, q);
    __shared__ float rs[4], rq[4];
    if ((tid & 63) == 0) { rs[tid >> 6] = s; rq[tid >> 6] = q; }
    __syncthreads();
    if (tid == 0) {
        float S = rs[0] + rs[1] + rs[2] + rs[3];
        float Q = rq[0] + rq[1] + rq[2] + rq[3];
        float m = S * invN;
        float v = Q * invN - m * m;
        stats[c] = m; stats[C + c] = v;
    }
}

// logits1 v2: block = (b, 256-hw chunk); each thread computes ALL 64 keys for its hw.
// c1 read exactly once. Writes wave-coalesced per key. (+pool in chunk-0 blocks)
__global__ __launch_bounds__(256) void logits1_kernel(
        const float* __restrict__ c1, const float* __restrict__ st,
        const float* __restrict__ g, const float* __restrict__ bb,
        const float* __restrict__ k1s, float* __restrict__ outL1,
        float* __restrict__ x1) {
    __shared__ float sk[384];
    __shared__ float ssc[6], ssh[6];
    int tid = threadIdx.x;
    if (tid < 6) {
        float m = st[tid], v = st[6 + tid];
        float sc = g[tid] * rsqrtf(v + EPSV);
        ssc[tid] = sc; ssh[tid] = bb[tid] - m * sc;
    }
    for (int i = tid; i < 384; i += 256) sk[i] = k1s[i];
    __syncthreads();
    int b = blockIdx.x >> 2, chunk = blockIdx.x & 3;
    int hw = chunk * 256 + tid;
    if (hw < 784) {
        float a[6];
#pragma unroll
        for (int c = 0; c < 6; ++c)
            a[c] = c1[(b * 6 + c) * 784 + hw] * ssc[c] + ssh[c];
        float* op = outL1 + (long)b * 50176 + hw;
#pragma unroll 8
        for (int k = 0; k < 64; ++k) {
            const float* kp = sk + k * 6;
            float d0 = a[0] - kp[0], d1 = a[1] - kp[1], d2 = a[2] - kp[2];
            float d3 = a[3] - kp[3], d4 = a[4] - kp[4], d5 = a[5] - kp[5];
            float s = d0 * d0 + d1 * d1 + d2 * d2 + d3 * d3 + d4 * d4 + d5 * d5;
            op[k * 784] = -sqrtf(s);
        }
    }
    // fused BN+relu+pool: chunk-0 block of each batch writes x1[b]
    if (chunk == 0) {
        const float* cp = c1 + b * 4704;
        for (int i = tid; i < 1176; i += 256) {
            int c = i / 196, p = i % 196, ph = p / 14, pw = p % 14;
            const float* ap = cp + c * 784 + ph * 56 + pw * 2;
            float sc = ssc[c], sh = ssh[c];
            float v0 = ap[0] * sc + sh, v1 = ap[1] * sc + sh;
            float v2 = ap[28] * sc + sh, v3 = ap[29] * sc + sh;
            x1[b * 1176 + i] = fmaxf(fmaxf(fmaxf(v0, v1), fmaxf(v2, v3)), 0.f);
        }
    }
}

// conv2: x1 [B,6,14,14] -> raw c2 [B,16,10,10] + partials; block=(b,c), 128 thr
__global__ __launch_bounds__(128) void conv2_kernel(
        const float* __restrict__ x1, const float* __restrict__ w,
        const float* __restrict__ bias, float* __restrict__ c2,
        float* __restrict__ part) {
    int bc = blockIdx.x; int b = bc >> 4, c = bc & 15;
    int tid = threadIdx.x;  // 128
    __shared__ float xs[1176];
    __shared__ float ws[150];
    __shared__ float rs[2], rq[2];
    for (int i = tid; i < 1176; i += 128) xs[i] = x1[b * 1176 + i];
    for (int i = tid; i < 150; i += 128) ws[i] = w[c * 150 + i];
    __syncthreads();
    float val = 0.f;
    if (tid < 100) {
        int oh = tid / 10, ow = tid % 10;
        float acc = bias[c];
#pragma unroll
        for (int ic = 0; ic < 6; ++ic) {
            const float* xp = xs + ic * 196 + oh * 14 + ow;
            const float* wp = ws + ic * 25;
#pragma unroll
            for (int kh = 0; kh < 5; ++kh)
#pragma unroll
                for (int kw = 0; kw < 5; ++kw)
                    acc += xp[kh * 14 + kw] * wp[kh * 5 + kw];
        }
        c2[bc * 100 + tid] = acc;
        val = acc;
    }
    float s = val, sq = val * val;
    wave_reduce2(s, sq);
    if ((tid & 63) == 0) { rs[tid >> 6] = s; rq[tid >> 6] = sq; }
    __syncthreads();
    if (tid == 0) {
        part[bc * 2]     = rs[0] + rs[1];
        part[bc * 2 + 1] = rq[0] + rq[1];
    }
}

// logits2 (+fused pool -> x2 in 1-of-25 blocks); act2 staged BN'd in LDS
__global__ __launch_bounds__(256) void logits2_kernel(
        const float* __restrict__ c2, const float* __restrict__ st,
        const float* __restrict__ g, const float* __restrict__ bb,
        const float* __restrict__ k2s, float* __restrict__ outL2,
        float* __restrict__ x2) {
    __shared__ float sk[1024];
    __shared__ float sa[1600];
    __shared__ float ssc[16], ssh[16];
    int tid = threadIdx.x;
    int t0 = blockIdx.x * 256;
    int b = t0 / 6400;                       // constant per block (6400 % 256 == 0)
    if (tid < 16) {
        float m = st[tid], v = st[16 + tid];
        float sc = g[tid] * rsqrtf(v + EPSV);
        ssc[tid] = sc; ssh[tid] = bb[tid] - m * sc;
    }
    for (int i = tid; i < 1024; i += 256) sk[i] = k2s[i];
    __syncthreads();
    for (int i = tid; i < 1600; i += 256) {
        int c = i / 100;
        sa[i] = c2[b * 1600 + i] * ssc[c] + ssh[c];
    }
    __syncthreads();
    int t = t0 + tid;
    int hw = t % 100; int k = (t / 100) & 63;
    float s = 0.f;
#pragma unroll
    for (int c = 0; c < 16; ++c) { float d = sa[c * 100 + hw] - sk[k * 16 + c]; s += d * d; }
    outL2[t] = -sqrtf(s);
    if ((blockIdx.x % 25) == 0) {            // fused relu+pool from BN'd LDS tile
        for (int i = tid; i < 400; i += 256) {
            int c = i / 25, p = i % 25, ph = p / 5, pw = p % 5;
            const float* ap = sa + c * 100 + ph * 20 + pw * 2;
            float m = fmaxf(fmaxf(ap[0], ap[1]), fmaxf(ap[10], ap[11]));
            x2[b * 400 + i] = fmaxf(m, 0.f);
        }
    }
}

// head: fc1 + act4 + logits3 + argmax + rank-based NG loss; block per b, 512 thr.
// All global reads coalesced via pre-transposed w1T [400][120] / k3sT [120][512].
__global__ __launch_bounds__(512) void head_kernel(
        const float* __restrict__ x2, const float* __restrict__ w1t,
        const float* __restrict__ b1, const float* __restrict__ w2,
        const float* __restrict__ b2, const float* __restrict__ k3st,
        float* __restrict__ outAct4, float* __restrict__ outL3,
        float* __restrict__ outAssign, float* __restrict__ lossb) {
    int b = blockIdx.x, tid = threadIdx.x;
    int lane = tid & 63, wid = tid >> 6;
    __shared__ float xs[400];
    __shared__ float partq[4][128];
    __shared__ float a3r[120], a3p[120];
    __shared__ float sv[512];
    __shared__ float wsum[8], wmv[8];
    __shared__ int wmi[8];
    for (int i = tid; i < 400; i += 512) xs[i] = x2[b * 400 + i];
    __syncthreads();
    // fc1: 4-way K-split; thread (q = tid>>7, o = tid&127) does dims [q*100, q*100+100)
    {
        int o = tid & 127, q = tid >> 7;
        float s = 0.f;
        if (o < 120) {
            const float* wp = w1t + q * 100 * 120 + o;
            const float* xp = xs + q * 100;
#pragma unroll 10
            for (int c = 0; c < 100; ++c) s += xp[c] * wp[c * 120];
        }
        partq[q][o] = s;
    }
    __syncthreads();
    if (tid < 120) {
        float acc = partq[0][tid] + partq[1][tid] + partq[2][tid] + partq[3][tid] + b1[tid];
        a3r[tid] = acc;
        a3p[tid] = fmaxf(acc, 0.f);
    }
    __syncthreads();
    // logits3: thread = key; k3sT reads lane-consecutive (coalesced), a3r broadcast
    float v;
    {
        const float* kp = k3st + tid;
        float s = 0.f;
#pragma unroll 8
        for (int c = 0; c < 120; ++c) { float d = a3r[c] - kp[c * 512]; s += d * d; }
        v = -sqrtf(s);
        sv[tid] = v;
        outL3[b * 512 + tid] = v;
    }
    if (tid < 10) {                           // fc2 from relu(act3)
        float acc = b2[tid];
        const float* wp = w2 + tid * 120;
#pragma unroll 8
        for (int c = 0; c < 120; ++c) acc += a3p[c] * wp[c];
        outAct4[b * 10 + tid] = acc;
    }
    __syncthreads();
    // rank of this thread's value (ties by index) == its sorted position.
    const float4* sv4 = reinterpret_cast<const float4*>(sv);
    int cnt = 0;
#pragma unroll 8
    for (int j4 = 0; j4 < 128; ++j4) {
        float4 o4 = sv4[j4];
        int jb = j4 * 4;
        cnt += (o4.x < v || (o4.x == v && jb < tid)) ? 1 : 0;
        cnt += (o4.y < v || (o4.y == v && jb + 1 < tid)) ? 1 : 0;
        cnt += (o4.z < v || (o4.z == v && jb + 2 < tid)) ? 1 : 0;
        cnt += (o4.w < v || (o4.w == v && jb + 3 < tid)) ? 1 : 0;
    }
    float contrib = v * v * expf(-(float)cnt);
    float ssum = contrib;
#pragma unroll
    for (int o = 32; o > 0; o >>= 1) ssum += __shfl_down(ssum, o, 64);
    float mv = v; int mi = tid;
#pragma unroll
    for (int o = 32; o > 0; o >>= 1) {
        float ov = __shfl_down(mv, o, 64);
        int oi = __shfl_down(mi, o, 64);
        if (ov > mv || (ov == mv && oi < mi)) { mv = ov; mi = oi; }
    }
    if (lane == 0) { wsum[wid] = ssum; wmv[wid] = mv; wmi[wid] = mi; }
    __syncthreads();
    if (tid == 0) {
        float tot = 0.f;
        float bmv = wmv[0]; int bmi = wmi[0];
#pragma unroll
        for (int w = 0; w < 8; ++w) {
            tot += wsum[w];
            if (wmv[w] > bmv || (wmv[w] == bmv && wmi[w] < bmi)) { bmv = wmv[w]; bmi = wmi[w]; }
        }
        lossb[b] = tot;
        outAssign[b] = (float)bmi;
    }
}

__global__ void final_kernel(const float* __restrict__ loss_b, float* __restrict__ out_loss) {
    __shared__ float r[256];
    int tid = threadIdx.x;
    r[tid] = loss_b[tid];
    __syncthreads();
    for (int s = 128; s > 0; s >>= 1) {
        if (tid < s) r[tid] += r[tid + s];
        __syncthreads();
    }
    if (tid == 0) out_loss[0] = r[0] / 256.f;
}

extern "C" void kernel_launch(void* const* d_in, const int* in_sizes, int n_in,
                              void* d_out, int out_size, void* d_ws, size_t ws_size,
                              hipStream_t stream) {
    const float* inp = (const float*)d_in[0];
    const float* c1w = (const float*)d_in[1];
    const float* c1b = (const float*)d_in[2];
    const float* g1  = (const float*)d_in[3];
    const float* bb1 = (const float*)d_in[4];
    const float* c2w = (const float*)d_in[5];
    const float* c2b = (const float*)d_in[6];
    const float* g2  = (const float*)d_in[7];
    const float* bb2 = (const float*)d_in[8];
    const float* f1w = (const float*)d_in[9];
    const float* f1b = (const float*)d_in[10];
    const float* f2w = (const float*)d_in[11];
    const float* f2b = (const float*)d_in[12];
    const float* k1  = (const float*)d_in[13];
    const float* k2  = (const float*)d_in[14];
    const float* k3  = (const float*)d_in[15];
    float* out = (float*)d_out;

    // workspace layout (floats) — ws is 256 MiB, use it; all bases 16B-aligned
    float* W = (float*)d_ws;
    float* c1raw = W;                   // 1204224
    float* x1    = c1raw + 1204224;     // 301056
    float* c2raw = x1 + 301056;         // 409600
    float* x2    = c2raw + 409600;      // 102400
    float* part1 = x2 + 102400;         // 3072
    float* part2 = part1 + 3072;        // 8192
    float* st1   = part2 + 8192;        // 16
    float* st2   = st1 + 16;            // 32
    float* lossb = st2 + 32;            // 256
    float* w1t   = lossb + 256;         // 48000  (w1T [400][120])
    float* k3st  = w1t + 48000;         // 61440  (k3sT [120][512])

    conv1_kernel<<<1964, 256, 0, stream>>>(inp, c1w, c1b, c1raw, part1,
                                           f1w, k3, w1t, k3st);
    stats_kernel<<<6, 256, 0, stream>>>(part1, st1, 6, 1.f / 200704.f);
    logits1_kernel<<<1024, 256, 0, stream>>>(c1raw, st1, g1, bb1, k1, out + OFF_L1, x1);
    conv2_kernel<<<B * 16, 128, 0, stream>>>(x1, c2w, c2b, c2raw, part2);
    stats_kernel<<<16, 256, 0, stream>>>(part2, st2, 16, 1.f / 25600.f);
    logits2_kernel<<<6400, 256, 0, stream>>>(c2raw, st2, g2, bb2, k2, out + OFF_L2, x2);
    head_kernel<<<B, 512, 0, stream>>>(x2, w1t, f1b, f2w, f2b, k3st,
                                       out + OFF_ACT4, out + OFF_L3, out + OFF_ASSIGN, lossb);
    final_kernel<<<1, 256, 0, stream>>>(lossb, out + OFF_LOSS);
}

// Round 10
// 94.489 us; speedup vs baseline: 1.2934x; 1.2692x over previous
//
#include <hip/hip_runtime.h>

#define B 256
#define EPSV 1e-5f

// ---------- output offsets (f32 elements) ----------
#define OFF_ASSIGN 0
#define OFF_LOSS   256
#define OFF_ACT4   257
#define OFF_L1     2817
#define OFF_L2     12847873
#define OFF_L3     14486273

__device__ inline void wave_reduce2(float& s, float& q) {
#pragma unroll
    for (int o = 32; o > 0; o >>= 1) {
        s += __shfl_down(s, o, 64);
        q += __shfl_down(q, o, 64);
    }
}

// conv1 (blocks 0..1535) + one-shot w1/k3s transpose (blocks 1536..1963)
__global__ __launch_bounds__(256) void conv1_kernel(
        const float* __restrict__ inp, const float* __restrict__ w,
        const float* __restrict__ bias, float* __restrict__ c1,
        float* __restrict__ part,
        const float* __restrict__ w1, const float* __restrict__ k3,
        float* __restrict__ w1t, float* __restrict__ k3st) {
    int bc = blockIdx.x;
    int tid = threadIdx.x;
    if (bc >= 1536) {                        // transpose tail blocks
        int idx = (bc - 1536) * 256 + tid;
        if (idx < 48000) {
            int c = idx / 120, o = idx % 120;
            w1t[idx] = w1[o * 400 + c];
        } else if (idx < 48000 + 61440) {
            int j = idx - 48000;
            int c = j >> 9, k = j & 511;
            k3st[j] = k3[k * 120 + c];
        }
        return;
    }
    int b = bc / 6, c = bc % 6;
    __shared__ float ws[75];
    __shared__ float rs[4], rq[4];
    if (tid < 75) ws[tid] = w[c * 75 + tid];
    __syncthreads();
    const float* ip = inp + b * 3072;
    float bs = bias[c];
    float s = 0.f, sq = 0.f;
    for (int hw = tid; hw < 784; hw += 256) {
        int oh = hw / 28, ow = hw % 28;
        float acc = bs;
#pragma unroll
        for (int ic = 0; ic < 3; ++ic) {
            const float* ipc = ip + ic * 1024 + oh * 32 + ow;
            const float* wc = ws + ic * 25;
#pragma unroll
            for (int kh = 0; kh < 5; ++kh)
#pragma unroll
                for (int kw = 0; kw < 5; ++kw)
                    acc += ipc[kh * 32 + kw] * wc[kh * 5 + kw];
        }
        c1[bc * 784 + hw] = acc;
        s += acc; sq += acc * acc;
    }
    wave_reduce2(s, sq);
    if ((tid & 63) == 0) { rs[tid >> 6] = s; rq[tid >> 6] = sq; }
    __syncthreads();
    if (tid == 0) {
        part[bc * 2]     = rs[0] + rs[1] + rs[2] + rs[3];
        part[bc * 2 + 1] = rq[0] + rq[1] + rq[2] + rq[3];
    }
}

// stage1: per-b block (1024 thr): redundant stats1 + BN(c1)->LDS + logits1 writes
// + pool->LDS + conv2 -> c2 global + per-(b,c) partials. No x1 in global memory.
__global__ __launch_bounds__(1024) void stage1_kernel(
        const float* __restrict__ c1raw, const float* __restrict__ part1,
        const float* __restrict__ g1, const float* __restrict__ bb1,
        const float* __restrict__ k1s,
        const float* __restrict__ c2w, const float* __restrict__ c2b,
        float* __restrict__ outL1, float* __restrict__ c2,
        float* __restrict__ part2) {
    int b = blockIdx.x, tid = threadIdx.x;
    int lane = tid & 63, wid = tid >> 6;     // 16 waves
    __shared__ float act[4704];              // BN'd act1 [6][784]
    __shared__ float sk[384];                // k1s
    __shared__ float w2s[2400];              // conv2 weights
    __shared__ float xp[1176];               // pooled x1 [6][14][14]
    __shared__ float sa[1600];               // raw conv2 out [16][100]
    __shared__ float chs[6], chq[6], ssc[6], ssh[6];
    // stats1: warps 0..5, channel = wid
    if (wid < 6) {
        float s = 0.f, q = 0.f;
#pragma unroll
        for (int j = 0; j < 4; ++j) {
            int bi = lane + 64 * j;
            s += part1[(bi * 6 + wid) * 2];
            q += part1[(bi * 6 + wid) * 2 + 1];
        }
        wave_reduce2(s, q);
        if (lane == 0) { chs[wid] = s; chq[wid] = q; }
    }
    for (int i = tid; i < 384; i += 1024) sk[i] = k1s[i];
    for (int i = tid; i < 2400; i += 1024) w2s[i] = c2w[i];
    __syncthreads();
    if (tid < 6) {
        float m = chs[tid] * (1.f / 200704.f);
        float v = chq[tid] * (1.f / 200704.f) - m * m;
        float sc = g1[tid] * rsqrtf(v + EPSV);
        ssc[tid] = sc; ssh[tid] = bb1[tid] - m * sc;
    }
    __syncthreads();
    const float* cp = c1raw + b * 4704;
    for (int i = tid; i < 4704; i += 1024) {
        int c = i / 784;
        act[i] = cp[i] * ssc[c] + ssh[c];
    }
    __syncthreads();
    // logits1: 50176 coalesced writes
    float* op = outL1 + (long)b * 50176;
    for (int i = tid; i < 50176; i += 1024) {
        int k = i / 784, hw = i - k * 784;
        const float* kp = sk + k * 6;
        float d0 = act[hw] - kp[0];
        float d1 = act[784 + hw] - kp[1];
        float d2 = act[1568 + hw] - kp[2];
        float d3 = act[2352 + hw] - kp[3];
        float d4 = act[3136 + hw] - kp[4];
        float d5 = act[3920 + hw] - kp[5];
        float s = d0 * d0 + d1 * d1 + d2 * d2 + d3 * d3 + d4 * d4 + d5 * d5;
        op[i] = -sqrtf(s);
    }
    // pool -> xp (LDS only)
    for (int i = tid; i < 1176; i += 1024) {
        int c = i / 196, p = i % 196, ph = p / 14, pw = p % 14;
        const float* ap = act + c * 784 + ph * 56 + pw * 2;
        float m = fmaxf(fmaxf(ap[0], ap[1]), fmaxf(ap[28], ap[29]));
        xp[i] = fmaxf(m, 0.f);
    }
    __syncthreads();
    // conv2 -> sa
    for (int i = tid; i < 1600; i += 1024) {
        int c = i / 100, hw = i - c * 100;
        int oh = hw / 10, ow = hw - oh * 10;
        float acc = c2b[c];
#pragma unroll
        for (int ic = 0; ic < 6; ++ic) {
            const float* xsrc = xp + ic * 196 + oh * 14 + ow;
            const float* wp = w2s + c * 150 + ic * 25;
#pragma unroll
            for (int kh = 0; kh < 5; ++kh)
#pragma unroll
                for (int kw = 0; kw < 5; ++kw)
                    acc += xsrc[kh * 14 + kw] * wp[kh * 5 + kw];
        }
        sa[i] = acc;
    }
    __syncthreads();
    for (int i = tid; i < 1600; i += 1024) c2[b * 1600 + i] = sa[i];
    // per-channel partials: warp = channel (16 warps)
    {
        float s = 0.f, q = 0.f;
        if (lane < 100) { float x = sa[wid * 100 + lane]; s = x; q = x * x; }
        if (lane < 36)  { float x = sa[wid * 100 + 64 + lane]; s += x; q += x * x; }
        wave_reduce2(s, q);
        if (lane == 0) {
            part2[(b * 16 + wid) * 2]     = s;
            part2[(b * 16 + wid) * 2 + 1] = q;
        }
    }
}

// stage2: per-b block (1024 thr): redundant stats2 + BN->LDS + logits2 writes
// + pool->LDS + fc1 + logits3 + act4 + rank-based NG loss + argmax.
__global__ __launch_bounds__(1024) void stage2_kernel(
        const float* __restrict__ c2, const float* __restrict__ part2,
        const float* __restrict__ g2, const float* __restrict__ bb2,
        const float* __restrict__ k2s,
        const float* __restrict__ w1t, const float* __restrict__ f1b,
        const float* __restrict__ f2w, const float* __restrict__ f2b,
        const float* __restrict__ k3st,
        float* __restrict__ outL2, float* __restrict__ outAct4,
        float* __restrict__ outL3, float* __restrict__ outAssign,
        float* __restrict__ lossb) {
    int b = blockIdx.x, tid = threadIdx.x;
    int lane = tid & 63, wid = tid >> 6;     // 16 waves
    __shared__ float sa[1600];               // BN'd act2
    __shared__ float sk[1024];               // k2s
    __shared__ float xs[400];                // pooled x2
    __shared__ float chs[16], chq[16], ssc[16], ssh[16];
    __shared__ float partq[8][128];
    __shared__ float a3r[120], a3p[120];
    __shared__ float pv[2][512];
    __shared__ float sv[512];
    __shared__ int   cntp[2][512];
    __shared__ float wsum[8], wmv[8];
    __shared__ int wmi[8];
    // stats2: warp = channel (16 warps)
    {
        float s = 0.f, q = 0.f;
#pragma unroll
        for (int j = 0; j < 4; ++j) {
            int bi = lane + 64 * j;
            s += part2[(bi * 16 + wid) * 2];
            q += part2[(bi * 16 + wid) * 2 + 1];
        }
        wave_reduce2(s, q);
        if (lane == 0) { chs[wid] = s; chq[wid] = q; }
    }
    for (int i = tid; i < 1024; i += 1024) sk[i] = k2s[i];
    __syncthreads();
    if (tid < 16) {
        float m = chs[tid] * (1.f / 25600.f);
        float v = chq[tid] * (1.f / 25600.f) - m * m;
        float sc = g2[tid] * rsqrtf(v + EPSV);
        ssc[tid] = sc; ssh[tid] = bb2[tid] - m * sc;
    }
    __syncthreads();
    for (int i = tid; i < 1600; i += 1024) {
        int c = i / 100;
        sa[i] = c2[b * 1600 + i] * ssc[c] + ssh[c];
    }
    __syncthreads();
    // logits2: 6400 coalesced writes
    float* op2 = outL2 + (long)b * 6400;
    for (int i = tid; i < 6400; i += 1024) {
        int k = i / 100, hw = i - k * 100;
        float s = 0.f;
#pragma unroll
        for (int c = 0; c < 16; ++c) {
            float d = sa[c * 100 + hw] - sk[k * 16 + c];
            s += d * d;
        }
        op2[i] = -sqrtf(s);
    }
    // pool -> xs (LDS only)
    for (int i = tid; i < 400; i += 1024) {
        int c = i / 25, p = i % 25, ph = p / 5, pw = p % 5;
        const float* ap = sa + c * 100 + ph * 20 + pw * 2;
        float m = fmaxf(fmaxf(ap[0], ap[1]), fmaxf(ap[10], ap[11]));
        xs[i] = fmaxf(m, 0.f);
    }
    __syncthreads();
    // fc1: 8-way K-split; thread (q8 = tid>>7, o = tid&127)
    {
        int o = tid & 127, q8 = tid >> 7;
        float s = 0.f;
        if (o < 120) {
            const float* wp = w1t + (q8 * 50) * 120 + o;
            const float* xp2 = xs + q8 * 50;
#pragma unroll 10
            for (int c = 0; c < 50; ++c) s += xp2[c] * wp[c * 120];
        }
        partq[q8][o] = s;
    }
    __syncthreads();
    if (tid < 120) {
        float acc = f1b[tid];
#pragma unroll
        for (int q8 = 0; q8 < 8; ++q8) acc += partq[q8][tid];
        a3r[tid] = acc;
        a3p[tid] = fmaxf(acc, 0.f);
    }
    __syncthreads();
    // logits3: 2 threads per key (halves of 120 dims); k3st column reads coalesced
    {
        int k = tid & 511, h = tid >> 9;
        const float* kp = k3st + k;
        float s = 0.f;
#pragma unroll 10
        for (int c = 0; c < 60; ++c) {
            int cc = h * 60 + c;
            float d = a3r[cc] - kp[cc * 512];
            s += d * d;
        }
        pv[h][k] = s;
    }
    if (tid < 10) {                           // fc2/act4 (tiny)
        float acc = f2b[tid];
        const float* wp = f2w + tid * 120;
#pragma unroll 8
        for (int c = 0; c < 120; ++c) acc += a3p[c] * wp[c];
        outAct4[b * 10 + tid] = acc;
    }
    __syncthreads();
    if (tid < 512) {
        float v = -sqrtf(pv[0][tid] + pv[1][tid]);
        sv[tid] = v;
        outL3[(long)b * 512 + tid] = v;
    }
    __syncthreads();
    // rank scan: 2 threads per value, each scans half the j-range
    {
        int i = tid & 511, h = tid >> 9;
        float v = sv[i];
        const float4* sv4 = reinterpret_cast<const float4*>(sv);
        int cnt = 0;
#pragma unroll 8
        for (int j4 = h * 64; j4 < h * 64 + 64; ++j4) {
            float4 o4 = sv4[j4];
            int jb = j4 * 4;
            cnt += (o4.x < v || (o4.x == v && jb < i)) ? 1 : 0;
            cnt += (o4.y < v || (o4.y == v && jb + 1 < i)) ? 1 : 0;
            cnt += (o4.z < v || (o4.z == v && jb + 2 < i)) ? 1 : 0;
            cnt += (o4.w < v || (o4.w == v && jb + 3 < i)) ? 1 : 0;
        }
        cntp[h][i] = cnt;
    }
    __syncthreads();
    if (tid < 512) {
        float v = sv[tid];
        int cnt = cntp[0][tid] + cntp[1][tid];
        float contrib = v * v * expf(-(float)cnt);
        float ssum = contrib;
#pragma unroll
        for (int o = 32; o > 0; o >>= 1) ssum += __shfl_down(ssum, o, 64);
        float mv = v; int mi = tid;
#pragma unroll
        for (int o = 32; o > 0; o >>= 1) {
            float ov = __shfl_down(mv, o, 64);
            int oi = __shfl_down(mi, o, 64);
            if (ov > mv || (ov == mv && oi < mi)) { mv = ov; mi = oi; }
        }
        if (lane == 0) { wsum[wid] = ssum; wmv[wid] = mv; wmi[wid] = mi; }
    }
    __syncthreads();
    if (tid == 0) {
        float tot = 0.f;
        float bmv = wmv[0]; int bmi = wmi[0];
#pragma unroll
        for (int w = 0; w < 8; ++w) {
            tot += wsum[w];
            if (wmv[w] > bmv || (wmv[w] == bmv && wmi[w] < bmi)) { bmv = wmv[w]; bmi = wmi[w]; }
        }
        lossb[b] = tot;
        outAssign[b] = (float)bmi;
    }
}

__global__ void final_kernel(const float* __restrict__ loss_b, float* __restrict__ out_loss) {
    __shared__ float r[256];
    int tid = threadIdx.x;
    r[tid] = loss_b[tid];
    __syncthreads();
    for (int s = 128; s > 0; s >>= 1) {
        if (tid < s) r[tid] += r[tid + s];
        __syncthreads();
    }
    if (tid == 0) out_loss[0] = r[0] / 256.f;
}

extern "C" void kernel_launch(void* const* d_in, const int* in_sizes, int n_in,
                              void* d_out, int out_size, void* d_ws, size_t ws_size,
                              hipStream_t stream) {
    const float* inp = (const float*)d_in[0];
    const float* c1w = (const float*)d_in[1];
    const float* c1b = (const float*)d_in[2];
    const float* g1  = (const float*)d_in[3];
    const float* bb1 = (const float*)d_in[4];
    const float* c2w = (const float*)d_in[5];
    const float* c2b = (const float*)d_in[6];
    const float* g2  = (const float*)d_in[7];
    const float* bb2 = (const float*)d_in[8];
    const float* f1w = (const float*)d_in[9];
    const float* f1b = (const float*)d_in[10];
    const float* f2w = (const float*)d_in[11];
    const float* f2b = (const float*)d_in[12];
    const float* k1  = (const float*)d_in[13];
    const float* k2  = (const float*)d_in[14];
    const float* k3  = (const float*)d_in[15];
    float* out = (float*)d_out;

    // workspace layout (floats); all bases 16B-aligned
    float* W = (float*)d_ws;
    float* c1raw = W;                   // 1204224
    float* part1 = c1raw + 1204224;     // 3072
    float* c2raw = part1 + 3072;        // 409600
    float* part2 = c2raw + 409600;      // 8192
    float* lossb = part2 + 8192;        // 256
    float* w1t   = lossb + 256;         // 48000  (w1T [400][120])
    float* k3st  = w1t + 48000;         // 61440  (k3sT [120][512])

    conv1_kernel<<<1964, 256, 0, stream>>>(inp, c1w, c1b, c1raw, part1,
                                           f1w, k3, w1t, k3st);
    stage1_kernel<<<B, 1024, 0, stream>>>(c1raw, part1, g1, bb1, k1, c2w, c2b,
                                          out + OFF_L1, c2raw, part2);
    stage2_kernel<<<B, 1024, 0, stream>>>(c2raw, part2, g2, bb2, k2,
                                          w1t, f1b, f2w, f2b, k3st,
                                          out + OFF_L2, out + OFF_ACT4,
                                          out + OFF_L3, out + OFF_ASSIGN, lossb);
    final_kernel<<<1, 256, 0, stream>>>(lossb, out + OFF_LOSS);
}